// Round 1
// baseline (401.332 us; speedup 1.0000x reference)
//
#include <hip/hip_runtime.h>

#define IN_F 4096
#define OUT_F 4096
#define BATCH 16384

// ws layout: ws[0..IN_F-1] = column sums of W, ws[IN_F] = bias sum.

// Kernel 1: column sums of W (row-major [OUT_F, IN_F]) + bias sum.
// grid = (4, 64), block = 256. Each thread owns one float4 column group
// (4*256 threads * 4 cols = 4096 cols), each blockIdx.y owns 64 rows.
__global__ __launch_bounds__(256) void colsum_kernel(
    const float* __restrict__ W, const float* __restrict__ bias,
    float* __restrict__ ws) {
  const int ROWS_PER_CHUNK = OUT_F / 64;  // 64
  int col4 = blockIdx.x * 256 + threadIdx.x;   // 0..1023 (float4 index)
  int row0 = blockIdx.y * ROWS_PER_CHUNK;
  const float4* W4 = (const float4*)W;

  float4 acc = make_float4(0.f, 0.f, 0.f, 0.f);
  #pragma unroll 8
  for (int r = 0; r < ROWS_PER_CHUNK; ++r) {
    float4 v = W4[(size_t)(row0 + r) * (IN_F / 4) + col4];
    acc.x += v.x; acc.y += v.y; acc.z += v.z; acc.w += v.w;
  }
  atomicAdd(&ws[col4 * 4 + 0], acc.x);
  atomicAdd(&ws[col4 * 4 + 1], acc.y);
  atomicAdd(&ws[col4 * 4 + 2], acc.z);
  atomicAdd(&ws[col4 * 4 + 3], acc.w);

  // Block (0,0) additionally reduces the bias vector.
  if (blockIdx.x == 0 && blockIdx.y == 0) {
    float b = 0.f;
    for (int i = threadIdx.x; i < OUT_F; i += 256) b += bias[i];
    #pragma unroll
    for (int off = 32; off > 0; off >>= 1) b += __shfl_down(b, off);
    if ((threadIdx.x & 63) == 0) atomicAdd(&ws[IN_F], b);
  }
}

// Kernel 2: out[row] = dot(x[row,:], colsum) + bias_sum.
// grid = 4096, block = 256 (4 waves, 1 row per wave).
__global__ __launch_bounds__(256) void rowdot_kernel(
    const float* __restrict__ x, const float* __restrict__ ws,
    float* __restrict__ out) {
  __shared__ float4 sw[IN_F / 4];  // 16 KiB
  __shared__ float sbias;

  const float4* ws4 = (const float4*)ws;
  for (int i = threadIdx.x; i < IN_F / 4; i += 256) sw[i] = ws4[i];
  if (threadIdx.x == 0) sbias = ws[IN_F];
  __syncthreads();

  int wave = threadIdx.x >> 6;
  int lane = threadIdx.x & 63;
  int row  = blockIdx.x * 4 + wave;

  const float4* xr = (const float4*)(x + (size_t)row * IN_F);
  float acc = 0.f;
  #pragma unroll
  for (int it = 0; it < IN_F / 4 / 64; ++it) {  // 16 iterations
    float4 xv = xr[it * 64 + lane];
    float4 wv = sw[it * 64 + lane];
    acc += xv.x * wv.x + xv.y * wv.y + xv.z * wv.z + xv.w * wv.w;
  }
  #pragma unroll
  for (int off = 32; off > 0; off >>= 1) acc += __shfl_down(acc, off);
  if (lane == 0) out[row] = acc + sbias;
}

extern "C" void kernel_launch(void* const* d_in, const int* in_sizes, int n_in,
                              void* d_out, int out_size, void* d_ws, size_t ws_size,
                              hipStream_t stream) {
  const float* x    = (const float*)d_in[0];
  const float* W    = (const float*)d_in[1];
  const float* bias = (const float*)d_in[2];
  float* out = (float*)d_out;
  float* ws  = (float*)d_ws;

  // Zero the accumulator workspace (harness re-poisons d_ws before each call).
  hipMemsetAsync(ws, 0, (IN_F + 1) * sizeof(float), stream);

  dim3 g1(4, 64);
  colsum_kernel<<<g1, 256, 0, stream>>>(W, bias, ws);

  rowdot_kernel<<<BATCH / 4, 256, 0, stream>>>(x, ws, out);
}